// Round 1
// baseline (1198.344 us; speedup 1.0000x reference)
//
#include <hip/hip_runtime.h>
#include <hip/hip_bf16.h>

// Problem: vanilla tanh RNN. B=64, T=2048, I=64, H=128, fp32.
//   xw[b,t,h] = sum_i x[b,t,i]*W[h,i] + b_ih[h] + b_hh[h]
//   h_t = tanh(xw_t + h_{t-1} @ U^T);  outputs: ys [B,T,H], h_last [B,H]
//
// d_out layout: [B*T*H] output floats, then [B*H] h_last floats.
// Kernel 1 writes xw into the output region (reused as scratch);
// kernel 2 consumes xw[t] and overwrites with h_t (read-before-write per addr).

#define RNN_B 64
#define RNN_T 2048
#define RNN_I 64
#define RNN_H 128

// ---------------------------------------------------------------------------
// Kernel 1: xw = x @ W^T + (b_ih + b_hh).  M=B*T=131072, N=128, K=64.
// 2048 blocks x 256 threads; 64 rows per block.
// W row for this thread's column lives in registers (64 floats);
// x tile staged in LDS, read as wave-uniform broadcast.
// ---------------------------------------------------------------------------
__global__ __launch_bounds__(256) void rnn_xw_gemm(
    const float* __restrict__ x, const float* __restrict__ W,
    const float* __restrict__ b_ih, const float* __restrict__ b_hh,
    float* __restrict__ xw) {
  const int tid = threadIdx.x;
  const int h  = tid & 127;   // output column
  const int rg = tid >> 7;    // row group (0/1)

  // W[h][0..63] into registers (one-time, L2-cached across blocks)
  const float4* W4 = (const float4*)(W + h * RNN_I);
  float4 w4[16];
#pragma unroll
  for (int j = 0; j < 16; ++j) w4[j] = W4[j];
  const float bias = b_ih[h] + b_hh[h];

  // Stage 64 rows of x (64x64 fp32 = 16 KB) into LDS, fully coalesced.
  __shared__ __align__(16) float4 xs[64 * 16];
  const long rbase = (long)blockIdx.x * 64;
  const float4* xg = (const float4*)(x + rbase * RNN_I);
#pragma unroll
  for (int j = 0; j < 4; ++j) xs[tid + 256 * j] = xg[tid + 256 * j];
  __syncthreads();

  // Each thread: 32 rows (stride 2), one column h. LDS reads broadcast.
  for (int rr = rg; rr < 64; rr += 2) {
    const float4* xr = xs + rr * 16;
    float4 a = make_float4(0.f, 0.f, 0.f, 0.f);
#pragma unroll
    for (int j = 0; j < 16; ++j) {
      float4 xv = xr[j];
      a.x = fmaf(w4[j].x, xv.x, a.x);
      a.y = fmaf(w4[j].y, xv.y, a.y);
      a.z = fmaf(w4[j].z, xv.z, a.z);
      a.w = fmaf(w4[j].w, xv.w, a.w);
    }
    float s = (a.x + a.y) + (a.z + a.w) + bias;
    xw[(rbase + rr) * RNN_H + h] = s;  // coalesced across lanes (consecutive h)
  }
}

// ---------------------------------------------------------------------------
// Kernel 2: sequential scan. One block per batch (64 blocks x 256 threads).
// Pair layout: thread -> (h = tid>>1, half = tid&1); each lane holds 64
// U coefficients in registers; partials reduced with one shfl_xor(1).
// h state double-buffered in LDS -> single barrier per timestep.
// xw prefetched 2 steps ahead. Writes out[b,t,h] over the consumed xw slot.
// ---------------------------------------------------------------------------
__global__ __launch_bounds__(256, 1) void rnn_scan(
    const float* xw,            // aliases `out` — no __restrict__ here
    float* out, float* __restrict__ hlast,
    const float* __restrict__ h0, const float* __restrict__ U) {
  const int b    = blockIdx.x;
  const int tid  = threadIdx.x;
  const int h    = tid >> 1;
  const int half = tid & 1;

  __shared__ __align__(16) float hbuf[2][RNN_H];

  // U[h][half*64 .. half*64+63] into registers (16 float4 = 64 VGPRs)
  const float4* U4 = (const float4*)(U + h * RNN_H + half * 64);
  float4 u4[16];
#pragma unroll
  for (int j = 0; j < 16; ++j) u4[j] = U4[j];

  if (tid < RNN_H) hbuf[0][tid] = h0[b * RNN_H + tid];

  const long base   = (long)b * RNN_T * RNN_H;
  const float* xwb  = xw + base + h;   // even lanes use (stride T*H per step)
  float* outb       = out + base + h;

  // depth-2 xw prefetch (even lanes only)
  float xv0 = 0.f, xv1 = 0.f;
  if (half == 0) {
    xv0 = xwb[0];
    xv1 = xwb[RNN_H];
  }
  __syncthreads();

  float last = 0.f;
  int cur = 0;
  for (int t = 0; t < RNN_T; ++t) {
    // prefetch xw[t+2]
    float xv2 = 0.f;
    if (half == 0) {
      int tp = t + 2;
      if (tp > RNN_T - 1) tp = RNN_T - 1;
      xv2 = xwb[(long)tp * RNN_H];
    }

    // 64-MAC partial dot: broadcast LDS reads (2 addrs/wave = conflict-free)
    const float4* hp = (const float4*)(&hbuf[cur][half * 64]);
    float4 a = make_float4(0.f, 0.f, 0.f, 0.f);
#pragma unroll
    for (int j = 0; j < 16; ++j) {
      float4 hv = hp[j];
      a.x = fmaf(u4[j].x, hv.x, a.x);
      a.y = fmaf(u4[j].y, hv.y, a.y);
      a.z = fmaf(u4[j].z, hv.z, a.z);
      a.w = fmaf(u4[j].w, hv.w, a.w);
    }
    float s = (a.x + a.y) + (a.z + a.w);
    s += __shfl_xor(s, 1);  // adjacent lanes hold the two halves of row h

    if (half == 0) {
      float val = tanhf(s + xv0);
      hbuf[cur ^ 1][h] = val;           // write next-state buffer
      outb[(long)t * RNN_H] = val;      // overwrite consumed xw slot
      last = val;
    }
    xv0 = xv1;
    xv1 = xv2;
    cur ^= 1;
    __syncthreads();  // single barrier: next-state visible before next read
  }
  if (half == 0) hlast[b * RNN_H + h] = last;
}

extern "C" void kernel_launch(void* const* d_in, const int* in_sizes, int n_in,
                              void* d_out, int out_size, void* d_ws, size_t ws_size,
                              hipStream_t stream) {
  const float* x    = (const float*)d_in[0];
  const float* h0   = (const float*)d_in[1];
  const float* W    = (const float*)d_in[2];
  const float* U    = (const float*)d_in[3];
  const float* b_ih = (const float*)d_in[4];
  const float* b_hh = (const float*)d_in[5];

  float* out   = (float*)d_out;                           // [B,T,H]
  float* hlast = out + (long)RNN_B * RNN_T * RNN_H;       // [B,H]

  // Stage 1: xw into the output region (scratch reuse; read-before-write in scan)
  rnn_xw_gemm<<<(RNN_B * RNN_T) / 64, 256, 0, stream>>>(x, W, b_ih, b_hh, out);
  // Stage 2: sequential recurrence, one block per batch element
  rnn_scan<<<RNN_B, 256, 0, stream>>>(out, out, hlast, h0, U);
}